// Round 4
// baseline (123.901 us; speedup 1.0000x reference)
//
#include <hip/hip_runtime.h>

// Problem constants (match reference)
#define NV 300000
#define FDIM 64
#define KN 9

// 16-lane sub-group per vertex, lane = 4 features (float4).
// Each 16-lane group processes TWO vertices (A, B) for 2x ILP:
// 8 vertices/wave, 32 per 256-thread block. NV % 32 == 0 -> no tail.

__device__ __forceinline__ float row16_reduce_add(float x) {
    // butterfly over 16 lanes, pure-VALU DPP; result broadcast to all 16
    int t;
    t = __builtin_amdgcn_update_dpp(0, __float_as_int(x), 0xB1, 0xF, 0xF, true);  // quad_perm xor1
    x += __int_as_float(t);
    t = __builtin_amdgcn_update_dpp(0, __float_as_int(x), 0x4E, 0xF, 0xF, true);  // quad_perm xor2
    x += __int_as_float(t);
    t = __builtin_amdgcn_update_dpp(0, __float_as_int(x), 0x141, 0xF, 0xF, true); // row_half_mirror
    x += __int_as_float(t);
    t = __builtin_amdgcn_update_dpp(0, __float_as_int(x), 0x140, 0xF, 0xF, true); // row_mirror
    x += __int_as_float(t);
    return x;
}

// broadcast lane ((lane&48)|K)'s value to its 16-lane group.
// ds_swizzle BitMode: offset = (xor<<10)|(or<<5)|and ; and=0x10 keeps bit4
// (the group bit within the 32-lane half), or=K forces lane bits 0..3 to K.
template <int K>
__device__ __forceinline__ int bcast16(int v) {
    return __builtin_amdgcn_ds_swizzle(v, (K << 5) | 0x10);
}

// compile-time unroll k=0..8 feeding a functor with integral constant
template <typename F, int... Ks>
__device__ __forceinline__ void for9_impl(F&& f, std::integer_sequence<int, Ks...>) {
    (f(std::integral_constant<int, Ks>{}), ...);
}
template <typename F>
__device__ __forceinline__ void for9(F&& f) {
    for9_impl(f, std::make_integer_sequence<int, KN>{});
}

__global__ __launch_bounds__(256) void aflow_kernel(
    const float* __restrict__ lattice_values,  // (N, F)
    const float* __restrict__ hidden_state,    // (N, F)
    const float* __restrict__ bias,            // (F,)
    const float* __restrict__ alpha_p,         // scalar
    const float* __restrict__ beta_p,          // scalar
    const int*   __restrict__ neighbor_idx,    // (N, K)
    float* __restrict__ out_aflow,             // (N, F)
    float* __restrict__ out_weights,           // (N, K)
    float* __restrict__ out_idx)               // (N, K) as float values
{
    const int lane = threadIdx.x & 63;
    const int wave = threadIdx.x >> 6;
    const int sub  = lane >> 4;   // 16-lane group within wave
    const int sl   = lane & 15;   // sub-lane: feature group (4 floats)

    const int nA = blockIdx.x * 32 + wave * 8 + sub;  // vertex A
    const int nB = nA + 4;                            // vertex B

    const float alpha = *alpha_p;
    const float beta  = *beta_p;
    const float ab    = alpha * beta;

    const float4* __restrict__ lv4 = (const float4*)lattice_values;
    const float4* __restrict__ hs4 = (const float4*)hidden_state;

    // --- loads: center rows + neighbor index rows (lanes sl<9) ---
    const float4 lvA = lv4[nA * 16 + sl];
    const float4 lvB = lv4[nB * 16 + sl];
    int idxrA = -1, idxrB = -1;
    if (sl < KN) {
        idxrA = neighbor_idx[nA * KN + sl];
        idxrB = neighbor_idx[nB * KN + sl];
    }

    // --- broadcast the 9 indices to all 16 lanes (static-pattern swizzle) ---
    int iA[KN], iB[KN];
    for9([&](auto kc) {
        constexpr int k = kc.value;
        iA[k] = bcast16<k>(idxrA);
        iB[k] = bcast16<k>(idxrB);
    });
    int vA = 0, vB = 0;
    #pragma unroll
    for (int k = 0; k < KN; ++k) {
        vA |= (iA[k] >= 0) ? (1 << k) : 0;
        vB |= (iB[k] >= 0) ? (1 << k) : 0;
    }

    // --- issue all 18 gathers (A first: vmcnt FIFO lets us compute A while B lands) ---
    float4 nghA[KN], nghB[KN];
    #pragma unroll
    for (int k = 0; k < KN; ++k) {
        const int ic = iA[k] >= 0 ? iA[k] : 0;
        nghA[k] = hs4[ic * 16 + sl];
    }
    #pragma unroll
    for (int k = 0; k < KN; ++k) {
        const int ic = iB[k] >= 0 ? iB[k] : 0;
        nghB[k] = hs4[ic * 16 + sl];
    }

    // --- vertex A: distances -> weights -> aggregate -> store ---
    float dA[KN];
    #pragma unroll
    for (int k = 0; k < KN; ++k) {
        const float4 h = nghA[k];
        float s = (h.x - lvA.x) * (h.x - lvA.x);
        s = fmaf(h.y - lvA.y, h.y - lvA.y, s);
        s = fmaf(h.z - lvA.z, h.z - lvA.z, s);
        s = fmaf(h.w - lvA.w, h.w - lvA.w, s);
        s = row16_reduce_add(s);
        dA[k] = ((vA >> k) & 1) ? sqrtf(s) : 0.0f;
    }
    float sumA = 0.0f;
    #pragma unroll
    for (int k = 0; k < KN; ++k) sumA += dA[k];
    const float invA = __builtin_amdgcn_rcpf(sumA);

    float4 accA = ((const float4*)bias)[sl];
    float woA = 0.0f;
    #pragma unroll
    for (int k = 0; k < KN; ++k) {
        const float dn = dA[k] * invA;
        float w = fmaf(-beta, fminf(dn, alpha), ab);   // (alpha - min(dn,alpha))*beta
        w = ((vA >> k) & 1) ? w : 0.0f;
        const float4 h = nghA[k];
        accA.x = fmaf(h.x, w, accA.x);
        accA.y = fmaf(h.y, w, accA.y);
        accA.z = fmaf(h.z, w, accA.z);
        accA.w = fmaf(h.w, w, accA.w);
        if (sl == k) woA = w;
    }
    ((float4*)out_aflow)[nA * 16 + sl] = accA;

    // --- vertex B: same ---
    float dB[KN];
    #pragma unroll
    for (int k = 0; k < KN; ++k) {
        const float4 h = nghB[k];
        float s = (h.x - lvB.x) * (h.x - lvB.x);
        s = fmaf(h.y - lvB.y, h.y - lvB.y, s);
        s = fmaf(h.z - lvB.z, h.z - lvB.z, s);
        s = fmaf(h.w - lvB.w, h.w - lvB.w, s);
        s = row16_reduce_add(s);
        dB[k] = ((vB >> k) & 1) ? sqrtf(s) : 0.0f;
    }
    float sumB = 0.0f;
    #pragma unroll
    for (int k = 0; k < KN; ++k) sumB += dB[k];
    const float invB = __builtin_amdgcn_rcpf(sumB);

    float4 accB = ((const float4*)bias)[sl];
    float woB = 0.0f;
    #pragma unroll
    for (int k = 0; k < KN; ++k) {
        const float dn = dB[k] * invB;
        float w = fmaf(-beta, fminf(dn, alpha), ab);
        w = ((vB >> k) & 1) ? w : 0.0f;
        const float4 h = nghB[k];
        accB.x = fmaf(h.x, w, accB.x);
        accB.y = fmaf(h.y, w, accB.y);
        accB.z = fmaf(h.z, w, accB.z);
        accB.w = fmaf(h.w, w, accB.w);
        if (sl == k) woB = w;
    }
    ((float4*)out_aflow)[nB * 16 + sl] = accB;

    // --- small outputs: weights + idx passthrough ---
    if (sl < KN) {
        out_weights[nA * KN + sl] = woA;
        out_weights[nB * KN + sl] = woB;
        out_idx[nA * KN + sl] = (float)idxrA;
        out_idx[nB * KN + sl] = (float)idxrB;
    }
}

extern "C" void kernel_launch(void* const* d_in, const int* in_sizes, int n_in,
                              void* d_out, int out_size, void* d_ws, size_t ws_size,
                              hipStream_t stream) {
    const float* lattice_values = (const float*)d_in[0];
    const float* hidden_state   = (const float*)d_in[1];
    const float* bias           = (const float*)d_in[2];
    const float* alpha          = (const float*)d_in[3];
    const float* beta           = (const float*)d_in[4];
    const int*   neighbor_idx   = (const int*)d_in[5];

    float* out = (float*)d_out;
    float* out_aflow   = out;                           // N*F
    float* out_weights = out + (size_t)NV * FDIM;       // N*K
    float* out_idx     = out_weights + (size_t)NV * KN; // N*K

    const int blocks = NV / 32;  // 32 vertices per 256-thread block (NV%32==0)
    aflow_kernel<<<blocks, 256, 0, stream>>>(
        lattice_values, hidden_state, bias, alpha, beta, neighbor_idx,
        out_aflow, out_weights, out_idx);
}

// Round 6
// 123.868 us; speedup vs baseline: 1.0003x; 1.0003x over previous
//
#include <hip/hip_runtime.h>

// Problem constants (match reference)
#define NV 300000
#define FDIM 64
#define KN 9

// native clang vector type (HIP float4 is a struct -> rejected by
// __builtin_nontemporal_*; this one is accepted and layout-identical)
typedef float f32x4 __attribute__((ext_vector_type(4)));

// 16-lane sub-group per vertex, lane = 4 features (f32x4).
// Each 16-lane group processes TWO vertices (A, B): 8 vertices/wave,
// 32 per 256-thread block. NV % 32 == 0 -> no tail.
// R6 = R4 + nontemporal streaming loads/stores (single-variable A/B vs R4).

__device__ __forceinline__ float row16_reduce_add(float x) {
    // butterfly over 16 lanes, pure-VALU DPP; result broadcast to all 16
    int t;
    t = __builtin_amdgcn_update_dpp(0, __float_as_int(x), 0xB1, 0xF, 0xF, true);  // quad_perm xor1
    x += __int_as_float(t);
    t = __builtin_amdgcn_update_dpp(0, __float_as_int(x), 0x4E, 0xF, 0xF, true);  // quad_perm xor2
    x += __int_as_float(t);
    t = __builtin_amdgcn_update_dpp(0, __float_as_int(x), 0x141, 0xF, 0xF, true); // row_half_mirror
    x += __int_as_float(t);
    t = __builtin_amdgcn_update_dpp(0, __float_as_int(x), 0x140, 0xF, 0xF, true); // row_mirror
    x += __int_as_float(t);
    return x;
}

// broadcast lane ((lane&48)|K)'s value to its 16-lane group.
// ds_swizzle BitMode: offset = (xor<<10)|(or<<5)|and ; and=0x10 keeps bit4,
// or=K forces lane bits 0..3 to K.
template <int K>
__device__ __forceinline__ int bcast16(int v) {
    return __builtin_amdgcn_ds_swizzle(v, (K << 5) | 0x10);
}

template <typename F, int... Ks>
__device__ __forceinline__ void for9_impl(F&& f, std::integer_sequence<int, Ks...>) {
    (f(std::integral_constant<int, Ks>{}), ...);
}
template <typename F>
__device__ __forceinline__ void for9(F&& f) {
    for9_impl(f, std::make_integer_sequence<int, KN>{});
}

__global__ __launch_bounds__(256) void aflow_kernel(
    const float* __restrict__ lattice_values,  // (N, F)
    const float* __restrict__ hidden_state,    // (N, F)
    const float* __restrict__ bias,            // (F,)
    const float* __restrict__ alpha_p,         // scalar
    const float* __restrict__ beta_p,          // scalar
    const int*   __restrict__ neighbor_idx,    // (N, K)
    float* __restrict__ out_aflow,             // (N, F)
    float* __restrict__ out_weights,           // (N, K)
    float* __restrict__ out_idx)               // (N, K) as float values
{
    const int lane = threadIdx.x & 63;
    const int wave = threadIdx.x >> 6;
    const int sub  = lane >> 4;   // 16-lane group within wave
    const int sl   = lane & 15;   // sub-lane: feature group (4 floats)

    const int nA = blockIdx.x * 32 + wave * 8 + sub;  // vertex A
    const int nB = nA + 4;                            // vertex B

    const float alpha = *alpha_p;
    const float beta  = *beta_p;
    const float ab    = alpha * beta;

    const f32x4* __restrict__ lv4 = (const f32x4*)lattice_values;
    const f32x4* __restrict__ hs4 = (const f32x4*)hidden_state;

    // --- streamed loads (read-once): nontemporal, keep out of L2 ---
    const f32x4 lvA = __builtin_nontemporal_load(&lv4[nA * 16 + sl]);
    const f32x4 lvB = __builtin_nontemporal_load(&lv4[nB * 16 + sl]);
    int idxrA = -1, idxrB = -1;
    if (sl < KN) {
        idxrA = __builtin_nontemporal_load(&neighbor_idx[nA * KN + sl]);
        idxrB = __builtin_nontemporal_load(&neighbor_idx[nB * KN + sl]);
    }

    // --- broadcast the 9 indices to all 16 lanes (static-pattern swizzle) ---
    int iA[KN], iB[KN];
    for9([&](auto kc) {
        constexpr int k = kc.value;
        iA[k] = bcast16<k>(idxrA);
        iB[k] = bcast16<k>(idxrB);
    });
    int vA = 0, vB = 0;
    #pragma unroll
    for (int k = 0; k < KN; ++k) {
        vA |= (iA[k] >= 0) ? (1 << k) : 0;
        vB |= (iB[k] >= 0) ? (1 << k) : 0;
    }

    // --- issue all 18 gathers (reused data; normal cached path) ---
    f32x4 nghA[KN], nghB[KN];
    #pragma unroll
    for (int k = 0; k < KN; ++k) {
        const int ic = iA[k] >= 0 ? iA[k] : 0;
        nghA[k] = hs4[ic * 16 + sl];
    }
    #pragma unroll
    for (int k = 0; k < KN; ++k) {
        const int ic = iB[k] >= 0 ? iB[k] : 0;
        nghB[k] = hs4[ic * 16 + sl];
    }

    // --- vertex A: distances -> weights -> aggregate -> store ---
    float dA[KN];
    #pragma unroll
    for (int k = 0; k < KN; ++k) {
        const f32x4 h = nghA[k];
        const f32x4 d = h - lvA;
        float s = d.x * d.x;
        s = fmaf(d.y, d.y, s);
        s = fmaf(d.z, d.z, s);
        s = fmaf(d.w, d.w, s);
        s = row16_reduce_add(s);
        dA[k] = ((vA >> k) & 1) ? sqrtf(s) : 0.0f;
    }
    float sumA = 0.0f;
    #pragma unroll
    for (int k = 0; k < KN; ++k) sumA += dA[k];
    const float invA = __builtin_amdgcn_rcpf(sumA);

    f32x4 accA = *(const f32x4*)&bias[sl * 4];
    float woA = 0.0f;
    #pragma unroll
    for (int k = 0; k < KN; ++k) {
        const float dn = dA[k] * invA;
        float w = fmaf(-beta, fminf(dn, alpha), ab);   // (alpha - min(dn,alpha))*beta
        w = ((vA >> k) & 1) ? w : 0.0f;
        const f32x4 h = nghA[k];
        accA.x = fmaf(h.x, w, accA.x);
        accA.y = fmaf(h.y, w, accA.y);
        accA.z = fmaf(h.z, w, accA.z);
        accA.w = fmaf(h.w, w, accA.w);
        if (sl == k) woA = w;
    }
    __builtin_nontemporal_store(accA, &((f32x4*)out_aflow)[nA * 16 + sl]);

    // --- vertex B: same ---
    float dB[KN];
    #pragma unroll
    for (int k = 0; k < KN; ++k) {
        const f32x4 h = nghB[k];
        const f32x4 d = h - lvB;
        float s = d.x * d.x;
        s = fmaf(d.y, d.y, s);
        s = fmaf(d.z, d.z, s);
        s = fmaf(d.w, d.w, s);
        s = row16_reduce_add(s);
        dB[k] = ((vB >> k) & 1) ? sqrtf(s) : 0.0f;
    }
    float sumB = 0.0f;
    #pragma unroll
    for (int k = 0; k < KN; ++k) sumB += dB[k];
    const float invB = __builtin_amdgcn_rcpf(sumB);

    f32x4 accB = *(const f32x4*)&bias[sl * 4];
    float woB = 0.0f;
    #pragma unroll
    for (int k = 0; k < KN; ++k) {
        const float dn = dB[k] * invB;
        float w = fmaf(-beta, fminf(dn, alpha), ab);
        w = ((vB >> k) & 1) ? w : 0.0f;
        const f32x4 h = nghB[k];
        accB.x = fmaf(h.x, w, accB.x);
        accB.y = fmaf(h.y, w, accB.y);
        accB.z = fmaf(h.z, w, accB.z);
        accB.w = fmaf(h.w, w, accB.w);
        if (sl == k) woB = w;
    }
    __builtin_nontemporal_store(accB, &((f32x4*)out_aflow)[nB * 16 + sl]);

    // --- small outputs: weights + idx passthrough ---
    if (sl < KN) {
        __builtin_nontemporal_store(woA, &out_weights[nA * KN + sl]);
        __builtin_nontemporal_store(woB, &out_weights[nB * KN + sl]);
        __builtin_nontemporal_store((float)idxrA, &out_idx[nA * KN + sl]);
        __builtin_nontemporal_store((float)idxrB, &out_idx[nB * KN + sl]);
    }
}

extern "C" void kernel_launch(void* const* d_in, const int* in_sizes, int n_in,
                              void* d_out, int out_size, void* d_ws, size_t ws_size,
                              hipStream_t stream) {
    const float* lattice_values = (const float*)d_in[0];
    const float* hidden_state   = (const float*)d_in[1];
    const float* bias           = (const float*)d_in[2];
    const float* alpha          = (const float*)d_in[3];
    const float* beta           = (const float*)d_in[4];
    const int*   neighbor_idx   = (const int*)d_in[5];

    float* out = (float*)d_out;
    float* out_aflow   = out;                           // N*F
    float* out_weights = out + (size_t)NV * FDIM;       // N*K
    float* out_idx     = out_weights + (size_t)NV * KN; // N*K

    const int blocks = NV / 32;  // 32 vertices per 256-thread block (NV%32==0)
    aflow_kernel<<<blocks, 256, 0, stream>>>(
        lattice_values, hidden_state, bias, alpha, beta, neighbor_idx,
        out_aflow, out_weights, out_idx);
}

// Round 7
// 95.899 us; speedup vs baseline: 1.2920x; 1.2916x over previous
//
#include <hip/hip_runtime.h>

// Problem constants (match reference)
#define NV 300000
#define FDIM 64
#define KN 9

typedef float f32x4 __attribute__((ext_vector_type(4)));

// ---------------- bf16 helpers ----------------
__device__ __forceinline__ unsigned int bf16_rne(float x) {
    unsigned int u = __float_as_uint(x);
    return u + 0x7FFFu + ((u >> 16) & 1u);   // round-to-nearest-even in high 16
}
// pack two floats -> [b1|b0] uint
__device__ __forceinline__ unsigned int bf16pair(float a, float b) {
    return (bf16_rne(a) >> 16) | (bf16_rne(b) & 0xFFFF0000u);
}
__device__ __forceinline__ f32x4 unpack_bf16x4(uint2 g) {
    f32x4 r;
    r.x = __uint_as_float(g.x << 16);
    r.y = __uint_as_float(g.x & 0xFFFF0000u);
    r.z = __uint_as_float(g.y << 16);
    r.w = __uint_as_float(g.y & 0xFFFF0000u);
    return r;
}

// ---------------- pre-pass: hidden_state f32 -> bf16 table ----------------
// 19.2M floats; each thread converts 4 -> one uint2 (8B). 4.8M threads.
__global__ __launch_bounds__(256) void compress_kernel(
    const float* __restrict__ hs, uint2* __restrict__ out)
{
    const int i = blockIdx.x * 256 + threadIdx.x;   // group of 4 floats
    const f32x4 v = ((const f32x4*)hs)[i];
    uint2 p;
    p.x = bf16pair(v.x, v.y);
    p.y = bf16pair(v.z, v.w);
    out[i] = p;
}

// ---------------- main kernel ----------------
__device__ __forceinline__ float row16_reduce_add(float x) {
    int t;
    t = __builtin_amdgcn_update_dpp(0, __float_as_int(x), 0xB1, 0xF, 0xF, true);  // quad_perm xor1
    x += __int_as_float(t);
    t = __builtin_amdgcn_update_dpp(0, __float_as_int(x), 0x4E, 0xF, 0xF, true);  // quad_perm xor2
    x += __int_as_float(t);
    t = __builtin_amdgcn_update_dpp(0, __float_as_int(x), 0x141, 0xF, 0xF, true); // row_half_mirror
    x += __int_as_float(t);
    t = __builtin_amdgcn_update_dpp(0, __float_as_int(x), 0x140, 0xF, 0xF, true); // row_mirror
    x += __int_as_float(t);
    return x;
}

template <int K>
__device__ __forceinline__ int bcast16(int v) {
    return __builtin_amdgcn_ds_swizzle(v, (K << 5) | 0x10);
}

template <typename F, int... Ks>
__device__ __forceinline__ void for9_impl(F&& f, std::integer_sequence<int, Ks...>) {
    (f(std::integral_constant<int, Ks>{}), ...);
}
template <typename F>
__device__ __forceinline__ void for9(F&& f) {
    for9_impl(f, std::make_integer_sequence<int, KN>{});
}

// USE_BF16: gather 128B bf16 rows from d_ws table; else 256B f32 rows.
template <bool USE_BF16>
__global__ __launch_bounds__(256) void aflow_kernel(
    const float* __restrict__ lattice_values,  // (N, F)
    const float* __restrict__ hidden_state,    // (N, F) f32
    const uint2* __restrict__ hidden_b16,      // (N, 16) packed bf16 rows
    const float* __restrict__ bias,            // (F,)
    const float* __restrict__ alpha_p,         // scalar
    const float* __restrict__ beta_p,          // scalar
    const int*   __restrict__ neighbor_idx,    // (N, K)
    float* __restrict__ out_aflow,             // (N, F)
    float* __restrict__ out_weights,           // (N, K)
    float* __restrict__ out_idx)               // (N, K) as float values
{
    const int lane = threadIdx.x & 63;
    const int wave = threadIdx.x >> 6;
    const int sub  = lane >> 4;   // 16-lane group within wave
    const int sl   = lane & 15;   // sub-lane: feature group (4 floats)

    const int nA = blockIdx.x * 32 + wave * 8 + sub;  // vertex A
    const int nB = nA + 4;                            // vertex B

    const float alpha = *alpha_p;
    const float beta  = *beta_p;
    const float ab    = alpha * beta;

    const f32x4* __restrict__ lv4 = (const f32x4*)lattice_values;
    const f32x4* __restrict__ hs4 = (const f32x4*)hidden_state;

    // --- streamed loads (read-once): nontemporal ---
    const f32x4 lvA = __builtin_nontemporal_load(&lv4[nA * 16 + sl]);
    const f32x4 lvB = __builtin_nontemporal_load(&lv4[nB * 16 + sl]);
    int idxrA = -1, idxrB = -1;
    if (sl < KN) {
        idxrA = __builtin_nontemporal_load(&neighbor_idx[nA * KN + sl]);
        idxrB = __builtin_nontemporal_load(&neighbor_idx[nB * KN + sl]);
    }

    // --- broadcast the 9 indices to all 16 lanes ---
    int iA[KN], iB[KN];
    for9([&](auto kc) {
        constexpr int k = kc.value;
        iA[k] = bcast16<k>(idxrA);
        iB[k] = bcast16<k>(idxrB);
    });
    int vA = 0, vB = 0;
    #pragma unroll
    for (int k = 0; k < KN; ++k) {
        vA |= (iA[k] >= 0) ? (1 << k) : 0;
        vB |= (iB[k] >= 0) ? (1 << k) : 0;
    }

    // --- issue all 18 gathers ---
    uint2 gA[KN], gB[KN];     // bf16 path: packed rows (2 VGPR each)
    f32x4 nghA[KN], nghB[KN]; // f32 path
    if (USE_BF16) {
        #pragma unroll
        for (int k = 0; k < KN; ++k) {
            const int ic = iA[k] >= 0 ? iA[k] : 0;
            gA[k] = hidden_b16[ic * 16 + sl];   // 128B row / sub-group
        }
        #pragma unroll
        for (int k = 0; k < KN; ++k) {
            const int ic = iB[k] >= 0 ? iB[k] : 0;
            gB[k] = hidden_b16[ic * 16 + sl];
        }
    } else {
        #pragma unroll
        for (int k = 0; k < KN; ++k) {
            const int ic = iA[k] >= 0 ? iA[k] : 0;
            nghA[k] = hs4[ic * 16 + sl];
        }
        #pragma unroll
        for (int k = 0; k < KN; ++k) {
            const int ic = iB[k] >= 0 ? iB[k] : 0;
            nghB[k] = hs4[ic * 16 + sl];
        }
    }

    // --- vertex A ---
    float dA[KN];
    #pragma unroll
    for (int k = 0; k < KN; ++k) {
        const f32x4 h = USE_BF16 ? unpack_bf16x4(gA[k]) : nghA[k];
        const f32x4 d = h - lvA;
        float s = d.x * d.x;
        s = fmaf(d.y, d.y, s);
        s = fmaf(d.z, d.z, s);
        s = fmaf(d.w, d.w, s);
        s = row16_reduce_add(s);
        dA[k] = ((vA >> k) & 1) ? sqrtf(s) : 0.0f;
    }
    float sumA = 0.0f;
    #pragma unroll
    for (int k = 0; k < KN; ++k) sumA += dA[k];
    const float invA = __builtin_amdgcn_rcpf(sumA);

    f32x4 accA = *(const f32x4*)&bias[sl * 4];
    float woA = 0.0f;
    #pragma unroll
    for (int k = 0; k < KN; ++k) {
        const float dn = dA[k] * invA;
        float w = fmaf(-beta, fminf(dn, alpha), ab);   // (alpha - min(dn,alpha))*beta
        w = ((vA >> k) & 1) ? w : 0.0f;
        const f32x4 h = USE_BF16 ? unpack_bf16x4(gA[k]) : nghA[k];
        accA.x = fmaf(h.x, w, accA.x);
        accA.y = fmaf(h.y, w, accA.y);
        accA.z = fmaf(h.z, w, accA.z);
        accA.w = fmaf(h.w, w, accA.w);
        if (sl == k) woA = w;
    }
    __builtin_nontemporal_store(accA, &((f32x4*)out_aflow)[nA * 16 + sl]);

    // --- vertex B ---
    float dB[KN];
    #pragma unroll
    for (int k = 0; k < KN; ++k) {
        const f32x4 h = USE_BF16 ? unpack_bf16x4(gB[k]) : nghB[k];
        const f32x4 d = h - lvB;
        float s = d.x * d.x;
        s = fmaf(d.y, d.y, s);
        s = fmaf(d.z, d.z, s);
        s = fmaf(d.w, d.w, s);
        s = row16_reduce_add(s);
        dB[k] = ((vB >> k) & 1) ? sqrtf(s) : 0.0f;
    }
    float sumB = 0.0f;
    #pragma unroll
    for (int k = 0; k < KN; ++k) sumB += dB[k];
    const float invB = __builtin_amdgcn_rcpf(sumB);

    f32x4 accB = *(const f32x4*)&bias[sl * 4];
    float woB = 0.0f;
    #pragma unroll
    for (int k = 0; k < KN; ++k) {
        const float dn = dB[k] * invB;
        float w = fmaf(-beta, fminf(dn, alpha), ab);
        w = ((vB >> k) & 1) ? w : 0.0f;
        const f32x4 h = USE_BF16 ? unpack_bf16x4(gB[k]) : nghB[k];
        accB.x = fmaf(h.x, w, accB.x);
        accB.y = fmaf(h.y, w, accB.y);
        accB.z = fmaf(h.z, w, accB.z);
        accB.w = fmaf(h.w, w, accB.w);
        if (sl == k) woB = w;
    }
    __builtin_nontemporal_store(accB, &((f32x4*)out_aflow)[nB * 16 + sl]);

    // --- small outputs ---
    if (sl < KN) {
        __builtin_nontemporal_store(woA, &out_weights[nA * KN + sl]);
        __builtin_nontemporal_store(woB, &out_weights[nB * KN + sl]);
        __builtin_nontemporal_store((float)idxrA, &out_idx[nA * KN + sl]);
        __builtin_nontemporal_store((float)idxrB, &out_idx[nB * KN + sl]);
    }
}

extern "C" void kernel_launch(void* const* d_in, const int* in_sizes, int n_in,
                              void* d_out, int out_size, void* d_ws, size_t ws_size,
                              hipStream_t stream) {
    const float* lattice_values = (const float*)d_in[0];
    const float* hidden_state   = (const float*)d_in[1];
    const float* bias           = (const float*)d_in[2];
    const float* alpha          = (const float*)d_in[3];
    const float* beta           = (const float*)d_in[4];
    const int*   neighbor_idx   = (const int*)d_in[5];

    float* out = (float*)d_out;
    float* out_aflow   = out;                           // N*F
    float* out_weights = out + (size_t)NV * FDIM;       // N*K
    float* out_idx     = out_weights + (size_t)NV * KN; // N*K

    const size_t tbl_bytes = (size_t)NV * FDIM * 2;     // 38.4 MB bf16 table
    const int blocks = NV / 32;  // 32 vertices per 256-thread block

    if (ws_size >= tbl_bytes) {
        uint2* tbl = (uint2*)d_ws;
        compress_kernel<<<(NV * FDIM / 4) / 256, 256, 0, stream>>>(hidden_state, tbl);
        aflow_kernel<true><<<blocks, 256, 0, stream>>>(
            lattice_values, hidden_state, tbl, bias, alpha, beta, neighbor_idx,
            out_aflow, out_weights, out_idx);
    } else {
        aflow_kernel<false><<<blocks, 256, 0, stream>>>(
            lattice_values, hidden_state, (const uint2*)d_ws, bias, alpha, beta, neighbor_idx,
            out_aflow, out_weights, out_idx);
    }
}